// Round 10
// baseline (234.488 us; speedup 1.0000x reference)
//
#include <hip/hip_runtime.h>
#include <math.h>

#define EMB   1024
#define HEADS 16
#define HD    64
#define SEQ   2048
#define BATCH 4
#define MTOT  (BATCH * SEQ)      // 8192 rows
#define XSZ   ((size_t)MTOT * EMB)   // 8388608
#define WSZ   ((size_t)EMB * EMB)    // 1048576

typedef __attribute__((ext_vector_type(8))) short s16x8;
typedef __attribute__((ext_vector_type(4))) short s16x4;
typedef __attribute__((ext_vector_type(4))) float f32x4;

__device__ __forceinline__ short f2bf(float f) {
    unsigned u = __builtin_bit_cast(unsigned, f);
    u += 0x7fffu + ((u >> 16) & 1u);     // RNE
    return (short)(u >> 16);
}

__device__ __forceinline__ unsigned pk_bf16(float a, float b) {
#if __has_builtin(__builtin_amdgcn_cvt_pk_bf16_f32)
    typedef __attribute__((ext_vector_type(2))) __bf16 bf16x2;
    return __builtin_bit_cast(unsigned, __builtin_amdgcn_cvt_pk_bf16_f32(a, b));
#else
    return (unsigned)(unsigned short)f2bf(a) |
           ((unsigned)(unsigned short)f2bf(b) << 16);
#endif
}

__device__ __forceinline__ float fexp2(float x) {
#if __has_builtin(__builtin_amdgcn_exp2f)
    return __builtin_amdgcn_exp2f(x);
#else
    return exp2f(x);
#endif
}

__device__ __forceinline__ void async16(const void* g, void* l) {
    __builtin_amdgcn_global_load_lds(
        (const __attribute__((address_space(1))) unsigned*)g,
        (__attribute__((address_space(3))) unsigned*)l, 16, 0, 0);
}

// ---------------------------------------------------------------------------
// fp32 -> bf16 conversion of x and the four weight matrices.
// Wq pre-scaled by log2(e)/sqrt(HD): softmax runs in exp2 domain.
// ---------------------------------------------------------------------------
__global__ __launch_bounds__(256)
void cvt_inputs(const float* __restrict__ x,  const float* __restrict__ wq,
                const float* __restrict__ wk, const float* __restrict__ wv,
                const float* __restrict__ wo, short* __restrict__ xb,
                short* __restrict__ wcat)
{
    const size_t e = ((size_t)blockIdx.x * 256 + threadIdx.x) * 8;
    const float* src;
    short* dst;
    float scale = 1.0f;
    if (e < XSZ) {
        src = x + e;
        dst = xb + e;
    } else {
        const size_t r = e - XSZ;
        const int w = (int)(r >> 20);            // WSZ = 2^20
        const size_t off = r & (WSZ - 1);
        src = (w == 0 ? wq : w == 1 ? wk : w == 2 ? wv : wo) + off;
        dst = wcat + r;
        if (w == 0) scale = 0.125f * 1.44269504f;   // 1/sqrt(64) * log2(e)
    }
    const float4 a = ((const float4*)src)[0];
    const float4 b = ((const float4*)src)[1];
    s16x8 v;
    v[0] = f2bf(a.x * scale); v[1] = f2bf(a.y * scale);
    v[2] = f2bf(a.z * scale); v[3] = f2bf(a.w * scale);
    v[4] = f2bf(b.x * scale); v[5] = f2bf(b.y * scale);
    v[6] = f2bf(b.z * scale); v[7] = f2bf(b.w * scale);
    *(s16x8*)dst = v;
}

#define BAR() __builtin_amdgcn_s_barrier()
#define WAIT_LGKM() do { asm volatile("s_waitcnt lgkmcnt(0)" ::: "memory"); \
                         __builtin_amdgcn_sched_barrier(0); } while (0)
#define WAIT_VM(n) asm volatile("s_waitcnt vmcnt(" #n ")" ::: "memory")

// ---------------------------------------------------------------------------
// GEMM: 256x128 / BK=32 / 3-buffer / ONE barrier per tile (attn-r9 pattern).
// Round-9 diagnosis: per-tile 1780 cyc vs {LDS 770, MFMA 620} budget — ~900
// cyc of waits (2 barriers + lgkm drain + dist-1 VM wait). New schedule per
// tile kt:
//   VM(3 counted)  — retires kt's 3 stores (invariant: outstanding entering
//                    kt = {kt(3), kt+1(3)}); VM(0) on the last tile.
//   BAR            — publishes kt (each wave retired its own stores first).
//   STG(kt+2)      — AFTER the barrier: targets the buffer read at kt-1,
//                    whose ds_reads completed at kt-1's lgkm(0) before every
//                    wave reached this barrier -> WAR-safe (proven in attn).
//   8 ds_read -> lgkm(0) -> 16 MFMA (setprio).
// Prefetch distance 2 iterations (~2800 cyc >> 900 HBM) -> VM wait ~ 0.
// LDS 3 x 24K = 72K -> 2 blocks/CU (144K <= 160K); regs identical to r9
// (56 VGPR + 64 AGPR = 120 <= 128 -> 4 waves/SIMD). No min-waves bound abuse.
// Epilogue: QKV=true -> bf16 Q|K (ldc 2048) + V transposed to vt[bh][d][s];
//           QKV=false -> f32 + bias (out-projection).
// ---------------------------------------------------------------------------
#define STG32(dst, k0) do { \
    async16(pA32 + (k0),                     (dst) + wv1024); \
    async16(pA32 + (size_t)128 * EMB + (k0), (dst) + 8192 + wv1024); \
    async16(pB32 + (k0),                     (dst) + 16384 + wv1024); \
} while (0)

template<bool QKV>
__global__ __launch_bounds__(512, 2)
void gemm_p32(const short* __restrict__ A, const short* __restrict__ B,
              void* __restrict__ C, int ldc, const float* __restrict__ bias,
              short* __restrict__ Vt)
{
    __shared__ __align__(16) char lds[73728];    // 3 bufs x 24 KiB (A16K|B8K)

    const int tid   = threadIdx.x;
    const int wv    = tid >> 6;
    const int lane  = tid & 63;
    const int col16 = lane & 15;
    const int quad  = lane >> 4;
    const int wm    = wv >> 1;       // 0..3  (64-row band)
    const int wn    = wv & 1;        // 0..1  (64-col band)
    const int wm4   = wm * 4;
    const int wn4   = wn * 4;
    const int wv1024 = wv << 10;

    // XCD-aware bijective swizzle (768 and 256 are both %8 == 0)
    const int nwg = gridDim.x * gridDim.y;
    int wg = blockIdx.y * gridDim.x + blockIdx.x;
    wg = (wg & 7) * (nwg >> 3) + (wg >> 3);
    const int rowBase = (wg / gridDim.x) * 256;
    const int colBase = (wg % gridDim.x) * 128;

    // st_16x32 swizzled ds_read per-lane base (within a 1 KiB 16x32 subtile)
    const int abase = (col16 * 64 + quad * 16) ^ ((col16 & 8) << 2);

    // staging: linear LDS dest, inverse-swizzled global source (r9-proven).
    const int rlane = (lane >> 2) & 15;
    const int colSt = ((lane & 3) << 3) ^ ((lane & 32) >> 1);
    const short* pA32 = A + (size_t)(rowBase + wv * 16 + rlane) * EMB + colSt;
    const short* pB32 = B + (size_t)(colBase + wv * 16 + rlane) * EMB + colSt;

    s16x8 a[4], bq[4];
    f32x4 acc[4][4];
#pragma unroll
    for (int i = 0; i < 4; ++i)
#pragma unroll
        for (int j = 0; j < 4; ++j) acc[i][j] = (f32x4){0.f, 0.f, 0.f, 0.f};

    char* b0 = lds;              // tile kt (read)
    char* b1 = lds + 24576;      // tile kt+1
    char* b2 = lds + 49152;      // stage target (kt+2)

    STG32(b0, 0);                // prologue: tiles 0 and 1 in flight (6)
    STG32(b1, 32);

    for (int kt = 0; kt < 32; ++kt) {
        const int k0 = kt << 5;

        if (kt + 1 < 32) { WAIT_VM(3); } else { WAIT_VM(0); }
        BAR();                               // publish tile kt
        __builtin_amdgcn_sched_barrier(0);
        if (kt + 2 < 32) STG32(b2, k0 + 64); // WAR-safe: follows barrier

#pragma unroll
        for (int mi = 0; mi < 4; ++mi)
            a[mi] = *(const s16x8*)(b0 + (wm4 + mi) * 1024 + abase);
#pragma unroll
        for (int ni = 0; ni < 4; ++ni)
            bq[ni] = *(const s16x8*)(b0 + 16384 + (wn4 + ni) * 1024 + abase);
        WAIT_LGKM();

        __builtin_amdgcn_s_setprio(1);
#pragma unroll
        for (int mi = 0; mi < 4; ++mi)
#pragma unroll
            for (int ni = 0; ni < 4; ++ni)
                acc[mi][ni] = __builtin_amdgcn_mfma_f32_16x16x32_bf16(
                    a[mi], bq[ni], acc[mi][ni], 0, 0, 0);
        __builtin_amdgcn_s_setprio(0);

        char* t = b0; b0 = b1; b1 = b2; b2 = t;
    }

    // ---- epilogue ----
    if (QKV) {
        short* Cb = (short*)C;
        if (colBase >= 2048) {
            // V band -> transposed store vt[(b*16+h)*64+d][s], s contiguous
#pragma unroll
            for (int mi = 0; mi < 4; ++mi) {
                const int rg0 = rowBase + wm * 64 + mi * 16 + quad * 4;
                const int bq_ = rg0 >> 11;
                const int s0 = rg0 & 2047;
#pragma unroll
                for (int ni = 0; ni < 4; ++ni) {
                    const int cg2 = colBase - 2048 + wn * 64 + ni * 16 + col16;
                    const int hh = cg2 >> 6, dd = cg2 & 63;
                    short* dst = Vt + (((size_t)(bq_ * 16 + hh) * 64 + dd) << 11) + s0;
                    const f32x4 v = acc[mi][ni];
                    uint2 pw;
                    pw.x = pk_bf16(v[0], v[1]);
                    pw.y = pk_bf16(v[2], v[3]);
                    *(uint2*)dst = pw;
                }
            }
        } else {
#pragma unroll
            for (int mi = 0; mi < 4; ++mi) {
                const int rg0 = rowBase + wm * 64 + mi * 16 + quad * 4;
#pragma unroll
                for (int ni = 0; ni < 4; ++ni) {
                    const int cg = colBase + wn * 64 + ni * 16 + col16;
                    const f32x4 v = acc[mi][ni];
#pragma unroll
                    for (int r = 0; r < 4; ++r)
                        Cb[(size_t)(rg0 + r) * ldc + cg] = f2bf(v[r]);
                }
            }
        }
    } else {
        float* Cf = (float*)C;
#pragma unroll
        for (int ni = 0; ni < 4; ++ni) {
            const int cg = colBase + wn * 64 + ni * 16 + col16;
            const float bj = bias ? bias[cg] : 0.f;
#pragma unroll
            for (int mi = 0; mi < 4; ++mi) {
                const int rg0 = rowBase + wm * 64 + mi * 16 + quad * 4;
                const f32x4 v = acc[mi][ni];
#pragma unroll
                for (int r = 0; r < 4; ++r)
                    Cf[(size_t)(rg0 + r) * ldc + cg] = v[r] + bj;
            }
        }
    }
}

// ---------------------------------------------------------------------------
// Flash-style causal attention (unchanged from round 9 — proven ~14 us gain).
// 512 threads = 8 waves, 16 queries/wave. Uniform pair {qx, 15-qx} = 34
// tiles/block; 512 blocks; LDS 64 KiB -> 2 blocks/CU by capacity. 3-buf KV,
// one barrier/tile, stage-after-barrier, counted VM(2).
// ---------------------------------------------------------------------------
#define LDT 2048
__global__ __launch_bounds__(512)
void attn_mfma(const short* __restrict__ QK, const short* __restrict__ VT,
               short* __restrict__ O)
{
    __shared__ __align__(16) short lKV[3][2][64 * 64];   // 48 KiB
    __shared__ __align__(16) short lP[8 * 16 * 64];      // 16 KiB

    char* lPc = (char*)lP;

    const int tid  = threadIdx.x;
    const int wv   = tid >> 6;           // 0..7
    const int lane = tid & 63;
    const int col  = lane & 15;
    const int quad = lane >> 4;
    const int csw  = (col & 7) << 4;     // read-side swizzle

    const int qpair = (int)blockIdx.x;   // 0..7
    const int bh = blockIdx.y;           // 0..63
    const int b  = bh >> 4;
    const int h  = bh & 15;
    const size_t baseq = (size_t)b * SEQ * LDT + (size_t)h * HD;
    const size_t basek = baseq + 1024;
    const size_t baseo = (size_t)b * SEQ * EMB + (size_t)h * HD;
    const short* vtb = VT + ((size_t)bh << 17);          // [64][2048]

    // staging: row = tid>>3, chunk = tid&7; source inverse-swizzled
    const int srow   = tid >> 3;
    const int schunk = tid & 7;
    const int ssc    = (schunk ^ (srow & 7)) * 8;
    const int sdst   = srow * 128 + schunk * 16;

    char* pwv = lPc + wv * 2048;         // 16 q rows x 128 B

    const s16x8 onesv = {0x3F80, 0x3F80, 0x3F80, 0x3F80,
                         0x3F80, 0x3F80, 0x3F80, 0x3F80};

#define STG(kt, bp) do { \
    async16(QK + basek + (size_t)((kt) * 64 + srow) * LDT + ssc, (char*)((bp)[0]) + sdst); \
    async16(vtb + (size_t)srow * LDT + (kt) * 64 + ssc,          (char*)((bp)[1]) + sdst); \
} while (0)

    for (int half = 0; half < 2; ++half) {
        const int qx = half ? (15 - qpair) : qpair;
        const int qb = qx * 128;
        const int qlo_w = qb + wv * 16;

        // Q fragments (B-operand: n=col -> query, k=quad*8+j). Pre-scaled.
        s16x8 qf[2];
        {
            const short* qr = QK + baseq + (size_t)(qlo_w + col) * LDT;
            qf[0] = *(const s16x8*)(qr + quad * 8);
            qf[1] = *(const s16x8*)(qr + 32 + quad * 8);
        }

        f32x4 of[4], lsum;
#pragma unroll
        for (int u = 0; u < 4; ++u) of[u] = (f32x4){0.f, 0.f, 0.f, 0.f};
        lsum = (f32x4){0.f, 0.f, 0.f, 0.f};

        const int nt = qb / 64 + 2;      // 2*qx + 2 key-tiles

        short (*b0)[64 * 64] = lKV[0];
        short (*b1)[64 * 64] = lKV[1];
        short (*b2)[64 * 64] = lKV[2];

        BAR();                           // close all prior compute
        __builtin_amdgcn_sched_barrier(0);
        STG(0, b0);
        STG(1, b1);

        for (int kt = 0; kt < nt; ++kt) {
            const int kb = kt * 64;
            if (kt + 1 < nt) { WAIT_VM(2); } else { WAIT_VM(0); }
            BAR();                       // publish tile kt; close kt-1 compute
            __builtin_amdgcn_sched_barrier(0);
            if (kt + 2 < nt) STG(kt + 2, b2);   // WAR-safe: follows barrier

            if (kb <= qlo_w + 15) {
                const char* lKb = (const char*)(b0[0]);
                const char* lVb = (const char*)(b0[1]);

                // K fragments
                s16x8 kf[4][2];
#pragma unroll
                for (int t = 0; t < 4; ++t) {
                    kf[t][0] = *(const s16x8*)(lKb + (t * 16 + col) * 128 + ((quad * 16) ^ csw));
                    kf[t][1] = *(const s16x8*)(lKb + (t * 16 + col) * 128 + ((64 + quad * 16) ^ csw));
                }

                // S^T = K·Q^T : C/D row = key(quad*4+r), col = query
                f32x4 s[4];
#pragma unroll
                for (int t = 0; t < 4; ++t) {
                    f32x4 acc = (f32x4){0.f, 0.f, 0.f, 0.f};
                    acc = __builtin_amdgcn_mfma_f32_16x16x32_bf16(kf[t][0], qf[0], acc, 0, 0, 0);
                    acc = __builtin_amdgcn_mfma_f32_16x16x32_bf16(kf[t][1], qf[1], acc, 0, 0, 0);
                    s[t] = acc;
                }

                const int qg = qlo_w + col;
                if (kb + 63 > qlo_w) {   // diagonal region: causal mask
#pragma unroll
                    for (int t = 0; t < 4; ++t)
#pragma unroll
                        for (int rr = 0; rr < 4; ++rr) {
                            const int kg = kb + t * 16 + quad * 4 + rr;
                            if (kg > qg) s[t][rr] = -3.0e38f;
                        }
                }

                // P = 2^S -> lP[q][key]
                char* pb = pwv + col * 128;
#pragma unroll
                for (int t = 0; t < 4; ++t) {
                    uint2 pkd;
                    pkd.x = pk_bf16(fexp2(s[t][0]), fexp2(s[t][1]));
                    pkd.y = pk_bf16(fexp2(s[t][2]), fexp2(s[t][3]));
                    *(uint2*)(pb + ((t * 32 + quad * 8) ^ csw)) = pkd;
                }

                // PV: O^T = mfma(A=V^T[d][key], B=P[q][key])
#pragma unroll
                for (int c = 0; c < 2; ++c) {
                    s16x8 vf[4];
#pragma unroll
                    for (int u = 0; u < 4; ++u)
                        vf[u] = *(const s16x8*)(lVb + (u * 16 + col) * 128 + ((c * 64 + quad * 16) ^ csw));
                    const s16x8 pa = *(const s16x8*)(pwv + col * 128 + ((c * 64 + quad * 16) ^ csw));
                    lsum = __builtin_amdgcn_mfma_f32_16x16x32_bf16(onesv, pa, lsum, 0, 0, 0);
#pragma unroll
                    for (int u = 0; u < 4; ++u)
                        of[u] = __builtin_amdgcn_mfma_f32_16x16x32_bf16(vf[u], pa, of[u], 0, 0, 0);
                }
            }

            short (*tmp)[64 * 64] = b0; b0 = b1; b1 = b2; b2 = tmp;
        }

        // ---- epilogue: per-lane normalize (query=col), b64 stores ----
        const float rl = 1.f / lsum[0];
        short* orow = O + baseo + (size_t)(qlo_w + col) * EMB + quad * 4;
#pragma unroll
        for (int u = 0; u < 4; ++u) {
            uint2 pkd;
            pkd.x = pk_bf16(of[u][0] * rl, of[u][1] * rl);
            pkd.y = pk_bf16(of[u][2] * rl, of[u][3] * rl);
            *(uint2*)&orow[u * 16] = pkd;
        }
    }
#undef STG
}

// ---------------------------------------------------------------------------
extern "C" void kernel_launch(void* const* d_in, const int* in_sizes, int n_in,
                              void* d_out, int out_size, void* d_ws, size_t ws_size,
                              hipStream_t stream)
{
    const float* x  = (const float*)d_in[0];
    const float* Wq = (const float*)d_in[1];
    const float* Wk = (const float*)d_in[2];
    const float* Wv = (const float*)d_in[3];
    const float* Wo = (const float*)d_in[4];
    const float* bo = (const float*)d_in[5];
    float* out = (float*)d_out;

    short* xb   = (short*)d_ws;                    // 16 MiB
    short* wcat = xb + XSZ;                        //  8 MiB
    short* qk   = wcat + 4 * WSZ;                  // 32 MiB  [token][2048] Q|K
    short* vt   = qk + (size_t)MTOT * 2048;        // 16 MiB  [bh][64][2048] V^T
    short* ob   = vt + (size_t)64 * 64 * 2048;     // 16 MiB

    const int cvt_blocks = (int)((XSZ + 4 * WSZ) / 8 / 256);   // 6144
    cvt_inputs<<<cvt_blocks, 256, 0, stream>>>(x, Wq, Wk, Wv, Wo, xb, wcat);

    // QKV projection: M=8192, N=3072, K=1024 -> 768 blocks, 2 blocks/CU capacity
    gemm_p32<true><<<dim3(3072 / 128, MTOT / 256), 512, 0, stream>>>(
        xb, wcat, qk, 2048, nullptr, vt);

    // attention: 512 uniform blocks (pair {x,15-x}), 8 waves, 2 blocks/CU
    attn_mfma<<<dim3(8, BATCH * HEADS), 512, 0, stream>>>(qk, vt, ob);

    // Output projection: M=8192, N=1024, K=1024 -> 256 blocks
    gemm_p32<false><<<dim3(EMB / 128, MTOT / 256), 512, 0, stream>>>(
        ob, wcat + (size_t)3 * WSZ, out, EMB, bo, nullptr);
}